// Round 1
// baseline (2134.623 us; speedup 1.0000x reference)
//
#include <hip/hip_runtime.h>

#define NN 50000
#define NE 800000
#define FIN 128
#define H 64
#define NG 64
#define NC 10
#define EPS 1e-5f

// ---------------- degree / dis ----------------
__global__ void count_deg_kernel(const int* __restrict__ dst, float* __restrict__ deg) {
    int e = blockIdx.x * blockDim.x + threadIdx.x;
    if (e < NE) atomicAdd(&deg[dst[e]], 1.0f);
}

__global__ void make_dis_kernel(float* __restrict__ deg) {
    int i = blockIdx.x * blockDim.x + threadIdx.x;
    if (i < NN) deg[i] = rsqrtf(deg[i] + 1.0f);
}

// ---------------- GEMM: out[N,H] = A[N,K] @ W[K,H] ----------------
template <int K>
__global__ __launch_bounds__(256) void gemm_kernel(const float* __restrict__ A,
                                                   const float* __restrict__ W,
                                                   float* __restrict__ outp) {
    __shared__ float Al[64][65];   // padded: bank = (row + k) % 32 -> conflict-free
    __shared__ float Wl[64 * H];
    const int tid = threadIdx.x;
    const int r0 = blockIdx.x * 64;
    const int row = tid >> 2;          // 0..63
    const int cb  = (tid & 3) << 4;    // col base: 0,16,32,48 (coalesced stores)
    float acc[16];
#pragma unroll
    for (int j = 0; j < 16; j++) acc[j] = 0.f;

    for (int k0 = 0; k0 < K; k0 += 64) {
#pragma unroll
        for (int idx = tid; idx < 64 * H; idx += 256) Wl[idx] = W[k0 * H + idx];
#pragma unroll
        for (int idx = tid; idx < 64 * 64; idx += 256) {
            int r = idx >> 6, c = idx & 63;
            int gr = r0 + r;
            Al[r][c] = (gr < NN) ? A[(long)gr * K + k0 + c] : 0.f;
        }
        __syncthreads();
#pragma unroll
        for (int k = 0; k < 64; k++) {
            float a = Al[row][k];
#pragma unroll
            for (int j = 0; j < 16; j++) acc[j] = fmaf(a, Wl[k * H + cb + j], acc[j]);
        }
        __syncthreads();
    }
    int gr = r0 + row;
    if (gr < NN) {
        float4* o = reinterpret_cast<float4*>(&outp[(long)gr * H + cb]);
        o[0] = make_float4(acc[0], acc[1], acc[2], acc[3]);
        o[1] = make_float4(acc[4], acc[5], acc[6], acc[7]);
        o[2] = make_float4(acc[8], acc[9], acc[10], acc[11]);
        o[3] = make_float4(acc[12], acc[13], acc[14], acc[15]);
    }
}

// ---------------- edge scatter: agg[dst] += hw[src] * dis[src]*dis[dst] ----------------
__global__ void scatter_kernel(const float* __restrict__ hw, const int* __restrict__ src,
                               const int* __restrict__ dst, const float* __restrict__ dis,
                               float* __restrict__ agg) {
    int gid = blockIdx.x * blockDim.x + threadIdx.x;
    int lane = gid & 63;
    int wid = gid >> 6;
    int nw = (gridDim.x * blockDim.x) >> 6;
    for (int e = wid; e < NE; e += nw) {
        int s = src[e];
        int d = dst[e];
        float norm = dis[s] * dis[d];
        atomicAdd(&agg[(long)d * H + lane], hw[(long)s * H + lane] * norm);
    }
}

// ---------------- layer-0 epilogue: h = relu(agg + hw*dis^2 + b) ----------------
__global__ void finish_relu_kernel(const float* __restrict__ agg, const float* __restrict__ hw,
                                   const float* __restrict__ dis, const float* __restrict__ b,
                                   float* __restrict__ h) {
    int i = blockIdx.x * blockDim.x + threadIdx.x;
    if (i < NN * H) {
        int n = i >> 6;
        float d2 = dis[n] * dis[n];
        float v = agg[i] + hw[i] * d2 + b[i & 63];
        h[i] = fmaxf(v, 0.f);
    }
}

// ---------------- hidden epilogue: conv (in-place into agg) + BN stats ----------------
__global__ __launch_bounds__(256) void finish_bnstats_kernel(float* __restrict__ agg,
                                                             const float* __restrict__ hw,
                                                             const float* __restrict__ dis,
                                                             const float* __restrict__ b,
                                                             float* __restrict__ bnst) {
    __shared__ float ls[H], lss[H];
    int tid = threadIdx.x;
    if (tid < H) { ls[tid] = 0.f; lss[tid] = 0.f; }
    __syncthreads();
    int gid = blockIdx.x * blockDim.x + tid;
    int stride = gridDim.x * blockDim.x;       // multiple of 64 -> ch fixed per thread
    int ch = gid & 63;
    float s = 0.f, sq = 0.f;
    for (int i = gid; i < NN * H; i += stride) {
        int n = i >> 6;
        float d2 = dis[n] * dis[n];
        float v = agg[i] + hw[i] * d2 + b[ch];
        agg[i] = v;
        s += v;
        sq += v * v;
    }
    atomicAdd(&ls[ch], s);
    atomicAdd(&lss[ch], sq);
    __syncthreads();
    if (tid < H) {
        atomicAdd(&bnst[tid], ls[tid]);
        atomicAdd(&bnst[H + tid], lss[tid]);
    }
}

// ---------------- BN + ReLU ----------------
__global__ void bn_relu_kernel(const float* __restrict__ conv, const float* __restrict__ bnst,
                               const float* __restrict__ gamma, const float* __restrict__ beta,
                               float* __restrict__ h) {
    int i = blockIdx.x * blockDim.x + threadIdx.x;
    if (i < NN * H) {
        int ch = i & 63;
        float mu = bnst[ch] * (1.0f / NN);
        float var = bnst[H + ch] * (1.0f / NN) - mu * mu;
        float v = (conv[i] - mu) * rsqrtf(var + EPS) * gamma[ch] + beta[ch];
        h[i] = fmaxf(v, 0.f);
    }
}

// ---------------- pooling ----------------
__global__ void pool_kernel(const float* __restrict__ h, const int* __restrict__ batch,
                            float* __restrict__ psum) {
    int i = blockIdx.x * blockDim.x + threadIdx.x;
    if (i < NN * H) {
        int n = i >> 6;
        atomicAdd(&psum[(long)batch[n] * H + (i & 63)], h[i]);
    }
}

__global__ void cnt_kernel(const int* __restrict__ batch, float* __restrict__ pcnt) {
    int i = blockIdx.x * blockDim.x + threadIdx.x;
    if (i < NN) atomicAdd(&pcnt[batch[i]], 1.0f);
}

// ---------------- MLP readout: 64 -> 32 -> 16 -> 10 ----------------
__global__ void mlp_kernel(const float* __restrict__ psum, const float* __restrict__ pcnt,
                           const float* __restrict__ W1, const float* __restrict__ b1,
                           const float* __restrict__ W2, const float* __restrict__ b2,
                           const float* __restrict__ W3, const float* __restrict__ b3,
                           float* __restrict__ out) {
    __shared__ float pooled[H], y1[32], y2[16];
    int g = blockIdx.x, t = threadIdx.x;
    float inv = 1.0f / fmaxf(pcnt[g], 1.0f);
    pooled[t] = psum[(long)g * H + t] * inv;
    __syncthreads();
    if (t < 32) {
        float s = b1[t];
        for (int k = 0; k < H; k++) s += pooled[k] * W1[k * 32 + t];
        y1[t] = fmaxf(s, 0.f);
    }
    __syncthreads();
    if (t < 16) {
        float s = b2[t];
        for (int k = 0; k < 32; k++) s += y1[k] * W2[k * 16 + t];
        y2[t] = fmaxf(s, 0.f);
    }
    __syncthreads();
    if (t < NC) {
        float s = b3[t];
        for (int k = 0; k < 16; k++) s += y2[k] * W3[k * NC + t];
        out[(long)g * NC + t] = s;
    }
}

extern "C" void kernel_launch(void* const* d_in, const int* in_sizes, int n_in,
                              void* d_out, int out_size, void* d_ws, size_t ws_size,
                              hipStream_t stream) {
    const float* x     = (const float*)d_in[0];
    const int*   ei    = (const int*)d_in[1];
    const int*   batch = (const int*)d_in[2];
    const float* W_in  = (const float*)d_in[3];
    const float* b_in  = (const float*)d_in[4];
    const float* W_hid = (const float*)d_in[5];
    const float* b_hid = (const float*)d_in[6];
    const float* gamma = (const float*)d_in[7];
    const float* beta  = (const float*)d_in[8];
    const float* W1    = (const float*)d_in[9];
    const float* b1    = (const float*)d_in[10];
    const float* W2    = (const float*)d_in[11];
    const float* b2    = (const float*)d_in[12];
    const float* W3    = (const float*)d_in[13];
    const float* b3    = (const float*)d_in[14];
    float* out = (float*)d_out;

    const int* src = ei;
    const int* dst = ei + NE;

    float* ws   = (float*)d_ws;
    float* dis  = ws;                 // NN (padded to 50048)
    float* hw   = dis + 50048;        // NN*H
    float* agg  = hw + (long)NN * H;  // NN*H
    float* h    = agg + (long)NN * H; // NN*H
    float* bnst = h + (long)NN * H;   // 2*H
    float* psum = bnst + 2 * H;       // NG*H
    float* pcnt = psum + NG * H;      // NG

    const int NB_ELT = (NN * H + 255) / 256;   // 12500
    const int NB_GEMM = (NN + 63) / 64;        // 782

    // degree -> dis
    hipMemsetAsync(dis, 0, NN * sizeof(float), stream);
    count_deg_kernel<<<(NE + 255) / 256, 256, 0, stream>>>(dst, dis);
    make_dis_kernel<<<(NN + 255) / 256, 256, 0, stream>>>(dis);

    // ---- layer 0: GCNConv(x, W_in) + ReLU ----
    gemm_kernel<FIN><<<NB_GEMM, 256, 0, stream>>>(x, W_in, hw);
    hipMemsetAsync(agg, 0, (size_t)NN * H * sizeof(float), stream);
    scatter_kernel<<<2048, 256, 0, stream>>>(hw, src, dst, dis, agg);
    finish_relu_kernel<<<NB_ELT, 256, 0, stream>>>(agg, hw, dis, b_in, h);

    // ---- hidden layers: GCNConv + BN + ReLU ----
    for (int l = 0; l < 3; l++) {
        gemm_kernel<H><<<NB_GEMM, 256, 0, stream>>>(h, W_hid + (long)l * H * H, hw);
        hipMemsetAsync(agg, 0, (size_t)NN * H * sizeof(float), stream);
        scatter_kernel<<<2048, 256, 0, stream>>>(hw, src, dst, dis, agg);
        hipMemsetAsync(bnst, 0, 2 * H * sizeof(float), stream);
        finish_bnstats_kernel<<<512, 256, 0, stream>>>(agg, hw, dis, b_hid + (long)l * H, bnst);
        bn_relu_kernel<<<NB_ELT, 256, 0, stream>>>(agg, bnst, gamma, beta, h);
    }

    // ---- pooling ----
    hipMemsetAsync(psum, 0, (NG * H + NG) * sizeof(float), stream);
    pool_kernel<<<NB_ELT, 256, 0, stream>>>(h, batch, psum);
    cnt_kernel<<<(NN + 255) / 256, 256, 0, stream>>>(batch, pcnt);

    // ---- MLP readout ----
    mlp_kernel<<<NG, H, 0, stream>>>(psum, pcnt, W1, b1, W2, b2, W3, b3, out);
}

// Round 6
// 1965.348 us; speedup vs baseline: 1.0861x; 1.0861x over previous
//
#include <hip/hip_runtime.h>

#define NN 50000
#define NE 800000
#define FIN 128
#define H 64
#define NG 64
#define NC 10
#define EPS 1e-5f
#define NB_SCAN 196          // ceil(NN/256)
#define GATHER_BLOCKS 12500  // NN/4 exactly

// ---------------- degree (int) ----------------
__global__ void count_deg_kernel(const int* __restrict__ dst, int* __restrict__ deg) {
    int e = blockIdx.x * blockDim.x + threadIdx.x;
    if (e < NE) atomicAdd(&deg[dst[e]], 1);
}

__global__ void make_dis_kernel(const int* __restrict__ deg, float* __restrict__ dis) {
    int i = blockIdx.x * blockDim.x + threadIdx.x;
    if (i < NN) dis[i] = rsqrtf((float)deg[i] + 1.0f);
}

// ---------------- 3-kernel exclusive scan of deg -> ebase ----------------
__global__ void scan1_kernel(const int* __restrict__ deg, int* __restrict__ ebase,
                             int* __restrict__ bsum) {
    __shared__ int s[256];
    int t = threadIdx.x;
    int i = blockIdx.x * 256 + t;
    int v = (i < NN) ? deg[i] : 0;
    s[t] = v;
    for (int off = 1; off < 256; off <<= 1) {
        __syncthreads();
        int add = (t >= off) ? s[t - off] : 0;
        __syncthreads();
        s[t] += add;
    }
    __syncthreads();
    if (i < NN) ebase[i] = s[t] - v;           // block-local exclusive
    if (t == 255) bsum[blockIdx.x] = s[255];   // block total
}

__global__ void scan2_kernel(int* __restrict__ bsum) {
    __shared__ int s[256];
    int t = threadIdx.x;
    int v = (t < NB_SCAN) ? bsum[t] : 0;
    s[t] = v;
    for (int off = 1; off < 256; off <<= 1) {
        __syncthreads();
        int add = (t >= off) ? s[t - off] : 0;
        __syncthreads();
        s[t] += add;
    }
    __syncthreads();
    if (t < NB_SCAN) bsum[t] = s[t] - v;       // exclusive
}

__global__ void scan3_kernel(int* __restrict__ ebase, const int* __restrict__ bsum) {
    int i = blockIdx.x * blockDim.x + threadIdx.x;
    if (i < NN) ebase[i] += bsum[i >> 8];
    if (i == 0) ebase[NN] = NE;
}

// ---------------- CSR fill (order within a node irrelevant for a sum) ----------------
__global__ void fill_kernel(const int* __restrict__ src, const int* __restrict__ dst,
                            const int* __restrict__ ebase, int* __restrict__ cursor,
                            const float* __restrict__ dis, int* __restrict__ eidx,
                            float* __restrict__ enorm) {
    int e = blockIdx.x * blockDim.x + threadIdx.x;
    if (e < NE) {
        int s = src[e], d = dst[e];
        int slot = ebase[d] + atomicAdd(&cursor[d], 1);
        eidx[slot] = s;
        enorm[slot] = dis[s] * dis[d];
    }
}

// ---------------- GEMM: out[N,H] = A[N,K] @ W[K,H] ----------------
template <int K>
__global__ __launch_bounds__(256, 4) void gemm_kernel(const float* __restrict__ A,
                                                      const float* __restrict__ W,
                                                      float* __restrict__ outp) {
    __shared__ float Al[64][65];
    __shared__ float Wl[64 * H];
    const int tid = threadIdx.x;
    const int r0 = blockIdx.x * 64;
    const int row = tid >> 2;
    const int cb  = (tid & 3) << 4;
    float acc[16];
#pragma unroll
    for (int j = 0; j < 16; j++) acc[j] = 0.f;

    for (int k0 = 0; k0 < K; k0 += 64) {
        for (int idx = tid; idx < 64 * H; idx += 256) Wl[idx] = W[k0 * H + idx];
        for (int idx = tid; idx < 64 * 64; idx += 256) {
            int r = idx >> 6, c = idx & 63;
            int gr = r0 + r;
            Al[r][c] = (gr < NN) ? A[(long)gr * K + k0 + c] : 0.f;
        }
        __syncthreads();
#pragma unroll
        for (int k = 0; k < 64; k++) {
            float a = Al[row][k];
#pragma unroll
            for (int j = 0; j < 16; j++) acc[j] = fmaf(a, Wl[k * H + cb + j], acc[j]);
        }
        __syncthreads();
    }
    int gr = r0 + row;
    if (gr < NN) {
        float4* o = reinterpret_cast<float4*>(&outp[(long)gr * H + cb]);
        o[0] = make_float4(acc[0], acc[1], acc[2], acc[3]);
        o[1] = make_float4(acc[4], acc[5], acc[6], acc[7]);
        o[2] = make_float4(acc[8], acc[9], acc[10], acc[11]);
        o[3] = make_float4(acc[12], acc[13], acc[14], acc[15]);
    }
}

// ---------------- CSR gather: one wave per node, lane = channel ----------------
// MODE 0: h = relu(conv + b)            (layer 0)
// MODE 1: conv stored raw + BN partials (hidden layers)
template <int MODE>
__global__ __launch_bounds__(256) void gather_kernel(const float* __restrict__ hw,
                                                     const int* __restrict__ ebase,
                                                     const int* __restrict__ eidx,
                                                     const float* __restrict__ enorm,
                                                     const float* __restrict__ dis,
                                                     const float* __restrict__ bias,
                                                     float* __restrict__ outp,
                                                     float* __restrict__ pbn) {
    const int node = blockIdx.x * 4 + (threadIdx.x >> 6);  // grid exact: node < NN
    const int lane = threadIdx.x & 63;
    const int e0 = ebase[node], e1 = ebase[node + 1];
    float acc = 0.f;
    for (int e = e0; e < e1; ++e) {
        acc = fmaf(hw[(long)eidx[e] * H + lane], enorm[e], acc);
    }
    float ds = dis[node];
    float v = fmaf(hw[(long)node * H + lane], ds * ds, acc) + bias[lane];
    if (MODE == 0) {
        outp[(long)node * H + lane] = fmaxf(v, 0.f);
    } else {
        outp[(long)node * H + lane] = v;
        __shared__ float ls[H], lss[H];
        if (threadIdx.x < H) { ls[threadIdx.x] = 0.f; lss[threadIdx.x] = 0.f; }
        __syncthreads();
        atomicAdd(&ls[lane], v);
        atomicAdd(&lss[lane], v * v);
        __syncthreads();
        if (threadIdx.x < H) {
            pbn[(long)blockIdx.x * 128 + threadIdx.x] = ls[threadIdx.x];
            pbn[(long)blockIdx.x * 128 + H + threadIdx.x] = lss[threadIdx.x];
        }
    }
}

// ---------------- reduce BN partials: one block per stat (128 stats) ----------------
__global__ void bnfin_kernel(const float* __restrict__ pbn, float* __restrict__ bnst) {
    int j = blockIdx.x;
    int t = threadIdx.x;
    float s = 0.f;
    for (int b = t; b < GATHER_BLOCKS; b += 256) s += pbn[(long)b * 128 + j];
    __shared__ float red[256];
    red[t] = s;
    __syncthreads();
    for (int off = 128; off; off >>= 1) {
        if (t < off) red[t] += red[t + off];
        __syncthreads();
    }
    if (t == 0) bnst[j] = red[0];
}

// ---------------- BN + ReLU ----------------
__global__ void bn_relu_kernel(const float* __restrict__ conv, const float* __restrict__ bnst,
                               const float* __restrict__ gamma, const float* __restrict__ beta,
                               float* __restrict__ h) {
    int i = blockIdx.x * blockDim.x + threadIdx.x;
    if (i < NN * H) {
        int ch = i & 63;
        float mu = bnst[ch] * (1.0f / NN);
        float var = bnst[H + ch] * (1.0f / NN) - mu * mu;
        float v = (conv[i] - mu) * rsqrtf(var + EPS) * gamma[ch] + beta[ch];
        h[i] = fmaxf(v, 0.f);
    }
}

// ---------------- graph boundaries via binary search (batch sorted) ----------------
__global__ void gstart_kernel(const int* __restrict__ batch, int* __restrict__ gstart) {
    int g = threadIdx.x;
    if (g <= NG) {
        int lo = 0, hi = NN;
        while (lo < hi) {
            int mid = (lo + hi) >> 1;
            if (batch[mid] < g) lo = mid + 1; else hi = mid;
        }
        gstart[g] = lo;
    }
}

// ---------------- pooling: one block per graph, no atomics ----------------
__global__ void pool_kernel(const float* __restrict__ h, const int* __restrict__ gstart,
                            float* __restrict__ pooled) {
    int g = blockIdx.x;
    int n0 = gstart[g], n1 = gstart[g + 1];
    int sub = threadIdx.x >> 6, lane = threadIdx.x & 63;
    float s = 0.f;
    for (int n = n0 + sub; n < n1; n += 4) s += h[(long)n * H + lane];
    __shared__ float red[256];
    red[threadIdx.x] = s;
    __syncthreads();
    if (sub == 0) {
        float tot = red[lane] + red[64 + lane] + red[128 + lane] + red[192 + lane];
        float inv = 1.0f / fmaxf((float)(n1 - n0), 1.0f);
        pooled[g * H + lane] = tot * inv;
    }
}

// ---------------- MLP readout: 64 -> 32 -> 16 -> 10 ----------------
__global__ void mlp_kernel(const float* __restrict__ pooled,
                           const float* __restrict__ W1, const float* __restrict__ b1,
                           const float* __restrict__ W2, const float* __restrict__ b2,
                           const float* __restrict__ W3, const float* __restrict__ b3,
                           float* __restrict__ out) {
    __shared__ float pl[H], y1[32], y2[16];
    int g = blockIdx.x, t = threadIdx.x;
    pl[t] = pooled[g * H + t];
    __syncthreads();
    if (t < 32) {
        float s = b1[t];
        for (int k = 0; k < H; k++) s += pl[k] * W1[k * 32 + t];
        y1[t] = fmaxf(s, 0.f);
    }
    __syncthreads();
    if (t < 16) {
        float s = b2[t];
        for (int k = 0; k < 32; k++) s += y1[k] * W2[k * 16 + t];
        y2[t] = fmaxf(s, 0.f);
    }
    __syncthreads();
    if (t < NC) {
        float s = b3[t];
        for (int k = 0; k < 16; k++) s += y2[k] * W3[k * NC + t];
        out[g * NC + t] = s;
    }
}

extern "C" void kernel_launch(void* const* d_in, const int* in_sizes, int n_in,
                              void* d_out, int out_size, void* d_ws, size_t ws_size,
                              hipStream_t stream) {
    const float* x     = (const float*)d_in[0];
    const int*   ei    = (const int*)d_in[1];
    const int*   batch = (const int*)d_in[2];
    const float* W_in  = (const float*)d_in[3];
    const float* b_in  = (const float*)d_in[4];
    const float* W_hid = (const float*)d_in[5];
    const float* b_hid = (const float*)d_in[6];
    const float* gamma = (const float*)d_in[7];
    const float* beta  = (const float*)d_in[8];
    const float* W1    = (const float*)d_in[9];
    const float* b1    = (const float*)d_in[10];
    const float* W2    = (const float*)d_in[11];
    const float* b2    = (const float*)d_in[12];
    const float* W3    = (const float*)d_in[13];
    const float* b3    = (const float*)d_in[14];
    float* out = (float*)d_out;

    const int* src = ei;
    const int* dst = ei + NE;

    // ---- workspace layout ----
    int*   deg_i  = (int*)d_ws;              // 50048
    int*   ebase  = deg_i + 50048;           // 50056 (NN+1)
    int*   cursor = ebase + 50056;           // 50048
    int*   eidx   = cursor + 50048;          // 800000
    int*   bsum   = eidx + 800000;           // 256
    int*   gstart = bsum + 256;              // 72
    float* dis    = (float*)(gstart + 72);   // 50048
    float* enorm  = dis + 50048;             // 800000
    float* hw     = enorm + 800000;          // NN*H
    float* conv   = hw + (long)NN * H;       // NN*H
    float* h      = conv + (long)NN * H;     // NN*H
    float* pbn    = h + (long)NN * H;        // 12500*128
    float* bnst   = pbn + (long)GATHER_BLOCKS * 128;  // 128
    float* pooled = bnst + 128;              // NG*H

    const int NB_ELT  = (NN * H + 255) / 256;  // 12500
    const int NB_GEMM = (NN + 63) / 64;        // 782
    const int NB_E    = (NE + 255) / 256;      // 3125
    const int NB_N    = (NN + 255) / 256;      // 196

    // ---- CSR build (once per launch) ----
    hipMemsetAsync(deg_i, 0, 50048 * sizeof(int), stream);
    hipMemsetAsync(cursor, 0, 50048 * sizeof(int), stream);
    count_deg_kernel<<<NB_E, 256, 0, stream>>>(dst, deg_i);
    make_dis_kernel<<<NB_N, 256, 0, stream>>>(deg_i, dis);
    scan1_kernel<<<NB_SCAN, 256, 0, stream>>>(deg_i, ebase, bsum);
    scan2_kernel<<<1, 256, 0, stream>>>(bsum);
    scan3_kernel<<<NB_N, 256, 0, stream>>>(ebase, bsum);
    fill_kernel<<<NB_E, 256, 0, stream>>>(src, dst, ebase, cursor, dis, eidx, enorm);
    gstart_kernel<<<1, 128, 0, stream>>>(batch, gstart);

    // ---- layer 0: GCNConv(x, W_in) + ReLU ----
    gemm_kernel<FIN><<<NB_GEMM, 256, 0, stream>>>(x, W_in, hw);
    gather_kernel<0><<<GATHER_BLOCKS, 256, 0, stream>>>(hw, ebase, eidx, enorm, dis, b_in, h, nullptr);

    // ---- hidden layers: GCNConv + BN + ReLU ----
    for (int l = 0; l < 3; l++) {
        gemm_kernel<H><<<NB_GEMM, 256, 0, stream>>>(h, W_hid + (long)l * H * H, hw);
        gather_kernel<1><<<GATHER_BLOCKS, 256, 0, stream>>>(hw, ebase, eidx, enorm, dis,
                                                            b_hid + (long)l * H, conv, pbn);
        bnfin_kernel<<<128, 256, 0, stream>>>(pbn, bnst);
        bn_relu_kernel<<<NB_ELT, 256, 0, stream>>>(conv, bnst, gamma, beta, h);
    }

    // ---- pooling + MLP ----
    pool_kernel<<<NG, 256, 0, stream>>>(h, gstart, pooled);
    mlp_kernel<<<NG, H, 0, stream>>>(pooled, W1, b1, W2, b2, W3, b3, out);
}

// Round 7
// 661.371 us; speedup vs baseline: 3.2276x; 2.9716x over previous
//
#include <hip/hip_runtime.h>

#define NN 50000
#define NE 800000
#define FIN 128
#define H 64
#define NG 64
#define NC 10
#define EPS 1e-5f
#define NB_SCAN 196          // ceil(NN/256)
#define GATHER_BLOCKS 12500  // NN/4 exactly
#define BNRED_BLOCKS 125     // 12500 = 125 * 100

// ---------------- degree (int) ----------------
__global__ void count_deg_kernel(const int* __restrict__ dst, int* __restrict__ deg) {
    int e = blockIdx.x * blockDim.x + threadIdx.x;
    if (e < NE) atomicAdd(&deg[dst[e]], 1);
}

__global__ void make_dis_kernel(const int* __restrict__ deg, float* __restrict__ dis) {
    int i = blockIdx.x * blockDim.x + threadIdx.x;
    if (i < NN) dis[i] = rsqrtf((float)deg[i] + 1.0f);
}

// ---------------- 3-kernel exclusive scan of deg -> ebase ----------------
__global__ void scan1_kernel(const int* __restrict__ deg, int* __restrict__ ebase,
                             int* __restrict__ bsum) {
    __shared__ int s[256];
    int t = threadIdx.x;
    int i = blockIdx.x * 256 + t;
    int v = (i < NN) ? deg[i] : 0;
    s[t] = v;
    for (int off = 1; off < 256; off <<= 1) {
        __syncthreads();
        int add = (t >= off) ? s[t - off] : 0;
        __syncthreads();
        s[t] += add;
    }
    __syncthreads();
    if (i < NN) ebase[i] = s[t] - v;
    if (t == 255) bsum[blockIdx.x] = s[255];
}

__global__ void scan2_kernel(int* __restrict__ bsum) {
    __shared__ int s[256];
    int t = threadIdx.x;
    int v = (t < NB_SCAN) ? bsum[t] : 0;
    s[t] = v;
    for (int off = 1; off < 256; off <<= 1) {
        __syncthreads();
        int add = (t >= off) ? s[t - off] : 0;
        __syncthreads();
        s[t] += add;
    }
    __syncthreads();
    if (t < NB_SCAN) bsum[t] = s[t] - v;
}

__global__ void scan3_kernel(int* __restrict__ ebase, const int* __restrict__ bsum) {
    int i = blockIdx.x * blockDim.x + threadIdx.x;
    if (i < NN) ebase[i] += bsum[i >> 8];
    if (i == 0) ebase[NN] = NE;
}

// ---------------- CSR fill ----------------
__global__ void fill_kernel(const int* __restrict__ src, const int* __restrict__ dst,
                            const int* __restrict__ ebase, int* __restrict__ cursor,
                            const float* __restrict__ dis, int* __restrict__ eidx,
                            float* __restrict__ enorm) {
    int e = blockIdx.x * blockDim.x + threadIdx.x;
    if (e < NE) {
        int s = src[e], d = dst[e];
        int slot = ebase[d] + atomicAdd(&cursor[d], 1);
        eidx[slot] = s;
        enorm[slot] = dis[s] * dis[d];
    }
}

// ---------------- GEMM layer 0: out[N,64] = x[N,128] @ W[128,64] ----------------
__global__ __launch_bounds__(256, 4) void gemm_fin_kernel(const float* __restrict__ A,
                                                          const float* __restrict__ W,
                                                          float* __restrict__ outp) {
    __shared__ float Al[64][65];
    __shared__ float Wl[64 * H];
    const int tid = threadIdx.x;
    const int r0 = blockIdx.x * 64;
    const int row = tid >> 2;
    const int cb  = (tid & 3) << 4;
    float acc[16];
#pragma unroll
    for (int j = 0; j < 16; j++) acc[j] = 0.f;

    for (int k0 = 0; k0 < FIN; k0 += 64) {
        for (int idx = tid; idx < 64 * H; idx += 256) Wl[idx] = W[k0 * H + idx];
        for (int idx = tid; idx < 64 * 64; idx += 256) {
            int r = idx >> 6, c = idx & 63;
            int gr = r0 + r;
            Al[r][c] = (gr < NN) ? A[(long)gr * FIN + k0 + c] : 0.f;
        }
        __syncthreads();
#pragma unroll
        for (int k = 0; k < 64; k++) {
            float a = Al[row][k];
#pragma unroll
            for (int j = 0; j < 16; j++) acc[j] = fmaf(a, Wl[k * H + cb + j], acc[j]);
        }
        __syncthreads();
    }
    int gr = r0 + row;
    if (gr < NN) {
        float4* o = reinterpret_cast<float4*>(&outp[(long)gr * H + cb]);
        o[0] = make_float4(acc[0], acc[1], acc[2], acc[3]);
        o[1] = make_float4(acc[4], acc[5], acc[6], acc[7]);
        o[2] = make_float4(acc[8], acc[9], acc[10], acc[11]);
        o[3] = make_float4(acc[12], acc[13], acc[14], acc[15]);
    }
}

// ---------------- hidden GEMM: out[N,64] = act(A)[N,64] @ W[64,64] ----------------
// DO_BN=1: act(a) = relu(a*scale[c] + shift[c]) applied during A staging (BN+ReLU fused)
template <int DO_BN>
__global__ __launch_bounds__(256, 4) void gemm_hid_kernel(const float* __restrict__ A,
                                                          const float* __restrict__ W,
                                                          const float* __restrict__ bnsc,
                                                          float* __restrict__ outp) {
    __shared__ float Al[64][65];
    __shared__ float Wl[64 * H];
    __shared__ float bns[128];
    const int tid = threadIdx.x;
    if (DO_BN && tid < 128) bns[tid] = bnsc[tid];
    const int r0 = blockIdx.x * 64;
    const int row = tid >> 2;
    const int cb  = (tid & 3) << 4;
    float acc[16];
#pragma unroll
    for (int j = 0; j < 16; j++) acc[j] = 0.f;

    if (DO_BN) __syncthreads();
    for (int idx = tid; idx < 64 * H; idx += 256) Wl[idx] = W[idx];
    for (int idx = tid; idx < 64 * 64; idx += 256) {
        int r = idx >> 6, c = idx & 63;
        int gr = r0 + r;
        float a = (gr < NN) ? A[(long)gr * H + c] : 0.f;
        if (DO_BN) a = fmaxf(fmaf(a, bns[c], bns[64 + c]), 0.f);
        Al[r][c] = a;
    }
    __syncthreads();
#pragma unroll
    for (int k = 0; k < 64; k++) {
        float a = Al[row][k];
#pragma unroll
        for (int j = 0; j < 16; j++) acc[j] = fmaf(a, Wl[k * H + cb + j], acc[j]);
    }
    int gr = r0 + row;
    if (gr < NN) {
        float4* o = reinterpret_cast<float4*>(&outp[(long)gr * H + cb]);
        o[0] = make_float4(acc[0], acc[1], acc[2], acc[3]);
        o[1] = make_float4(acc[4], acc[5], acc[6], acc[7]);
        o[2] = make_float4(acc[8], acc[9], acc[10], acc[11]);
        o[3] = make_float4(acc[12], acc[13], acc[14], acc[15]);
    }
}

// ---------------- CSR gather: wave per node, 4 edges in flight (16 lanes x float4) ----
// MODE 0: h = relu(v + b)                  (layer 0 epilogue)
// MODE 1: conv stored raw + BN partials    (hidden layers)
template <int MODE>
__global__ __launch_bounds__(256) void gather_kernel(const float* __restrict__ hw,
                                                     const int* __restrict__ ebase,
                                                     const int* __restrict__ eidx,
                                                     const float* __restrict__ enorm,
                                                     const float* __restrict__ dis,
                                                     const float* __restrict__ bias,
                                                     float* __restrict__ outp,
                                                     float* __restrict__ pbn) {
    __shared__ float ls[H], lss[H];
    if (MODE == 1) {
        if (threadIdx.x < H) { ls[threadIdx.x] = 0.f; lss[threadIdx.x] = 0.f; }
        __syncthreads();
    }
    const int node = blockIdx.x * 4 + (threadIdx.x >> 6);  // < NN exactly
    const int lane = threadIdx.x & 63;
    const int grp  = lane >> 4;          // edge sub-group 0..3
    const int c4   = (lane & 15) << 2;   // channel base
    const int e0 = ebase[node], e1 = ebase[node + 1];
    float4 acc = make_float4(0.f, 0.f, 0.f, 0.f);
    for (int e = e0 + grp; e < e1; e += 4) {
        float nrm = enorm[e];
        const float4 v = *reinterpret_cast<const float4*>(&hw[(long)eidx[e] * H + c4]);
        acc.x = fmaf(v.x, nrm, acc.x);
        acc.y = fmaf(v.y, nrm, acc.y);
        acc.z = fmaf(v.z, nrm, acc.z);
        acc.w = fmaf(v.w, nrm, acc.w);
    }
#pragma unroll
    for (int m = 16; m <= 32; m <<= 1) {
        acc.x += __shfl_xor(acc.x, m, 64);
        acc.y += __shfl_xor(acc.y, m, 64);
        acc.z += __shfl_xor(acc.z, m, 64);
        acc.w += __shfl_xor(acc.w, m, 64);
    }
    float ds = dis[node];
    float d2 = ds * ds;
    const float4 self = *reinterpret_cast<const float4*>(&hw[(long)node * H + c4]);
    float4 v;
    v.x = fmaf(self.x, d2, acc.x) + bias[c4 + 0];
    v.y = fmaf(self.y, d2, acc.y) + bias[c4 + 1];
    v.z = fmaf(self.z, d2, acc.z) + bias[c4 + 2];
    v.w = fmaf(self.w, d2, acc.w) + bias[c4 + 3];
    if (MODE == 0) {
        v.x = fmaxf(v.x, 0.f); v.y = fmaxf(v.y, 0.f);
        v.z = fmaxf(v.z, 0.f); v.w = fmaxf(v.w, 0.f);
    }
    if (grp == 0) {
        *reinterpret_cast<float4*>(&outp[(long)node * H + c4]) = v;
        if (MODE == 1) {
            atomicAdd(&ls[c4 + 0], v.x); atomicAdd(&lss[c4 + 0], v.x * v.x);
            atomicAdd(&ls[c4 + 1], v.y); atomicAdd(&lss[c4 + 1], v.y * v.y);
            atomicAdd(&ls[c4 + 2], v.z); atomicAdd(&lss[c4 + 2], v.z * v.z);
            atomicAdd(&ls[c4 + 3], v.w); atomicAdd(&lss[c4 + 3], v.w * v.w);
        }
    }
    if (MODE == 1) {
        __syncthreads();
        if (threadIdx.x < H) {
            pbn[(long)blockIdx.x * 128 + threadIdx.x] = ls[threadIdx.x];
            pbn[(long)blockIdx.x * 128 + H + threadIdx.x] = lss[threadIdx.x];
        }
    }
}

// ---------------- BN partial reduction, stage A (coalesced): 12500x128 -> 125x128 ----
__global__ void bnredA_kernel(const float* __restrict__ pbn, float* __restrict__ pbn2) {
    int c = threadIdx.x & 127;
    int half = threadIdx.x >> 7;
    int r0 = blockIdx.x * 100;
    float s = 0.f;
    for (int r = r0 + half; r < r0 + 100; r += 2) s += pbn[(long)r * 128 + c];
    __shared__ float red[256];
    red[threadIdx.x] = s;
    __syncthreads();
    if (half == 0) pbn2[(long)blockIdx.x * 128 + c] = red[c] + red[128 + c];
}

// ---------------- stage B: 125x128 -> scale/shift[128] ----------------
__global__ void bnredB_kernel(const float* __restrict__ pbn2, const float* __restrict__ gamma,
                              const float* __restrict__ beta, float* __restrict__ bnsc) {
    int t = threadIdx.x;
    int c = t & 127;
    int half = t >> 7;
    float s = 0.f;
    for (int r = half; r < BNRED_BLOCKS; r += 2) s += pbn2[(long)r * 128 + c];
    __shared__ float red[256];
    __shared__ float tot[128];
    red[t] = s;
    __syncthreads();
    if (t < 128) tot[t] = red[t] + red[128 + t];
    __syncthreads();
    if (t < H) {
        float mu  = tot[t] * (1.0f / NN);
        float var = tot[H + t] * (1.0f / NN) - mu * mu;
        float sc  = rsqrtf(var + EPS) * gamma[t];
        bnsc[t]     = sc;
        bnsc[H + t] = beta[t] - mu * sc;
    }
}

// ---------------- graph boundaries (batch sorted) ----------------
__global__ void gstart_kernel(const int* __restrict__ batch, int* __restrict__ gstart) {
    int g = threadIdx.x;
    if (g <= NG) {
        int lo = 0, hi = NN;
        while (lo < hi) {
            int mid = (lo + hi) >> 1;
            if (batch[mid] < g) lo = mid + 1; else hi = mid;
        }
        gstart[g] = lo;
    }
}

// ---------------- pooling with fused BN+ReLU: block per graph ----------------
__global__ void pool_bn_kernel(const float* __restrict__ conv, const float* __restrict__ bnsc,
                               const int* __restrict__ gstart, float* __restrict__ pooled) {
    int g = blockIdx.x;
    int n0 = gstart[g], n1 = gstart[g + 1];
    int sub = threadIdx.x >> 6, lane = threadIdx.x & 63;
    float sc = bnsc[lane], sh = bnsc[H + lane];
    float s = 0.f;
    for (int n = n0 + sub; n < n1; n += 4)
        s += fmaxf(fmaf(conv[(long)n * H + lane], sc, sh), 0.f);
    __shared__ float red[256];
    red[threadIdx.x] = s;
    __syncthreads();
    if (sub == 0) {
        float tot = red[lane] + red[64 + lane] + red[128 + lane] + red[192 + lane];
        float inv = 1.0f / fmaxf((float)(n1 - n0), 1.0f);
        pooled[g * H + lane] = tot * inv;
    }
}

// ---------------- MLP readout: 64 -> 32 -> 16 -> 10 ----------------
__global__ void mlp_kernel(const float* __restrict__ pooled,
                           const float* __restrict__ W1, const float* __restrict__ b1,
                           const float* __restrict__ W2, const float* __restrict__ b2,
                           const float* __restrict__ W3, const float* __restrict__ b3,
                           float* __restrict__ out) {
    __shared__ float pl[H], y1[32], y2[16];
    int g = blockIdx.x, t = threadIdx.x;
    pl[t] = pooled[g * H + t];
    __syncthreads();
    if (t < 32) {
        float s = b1[t];
        for (int k = 0; k < H; k++) s += pl[k] * W1[k * 32 + t];
        y1[t] = fmaxf(s, 0.f);
    }
    __syncthreads();
    if (t < 16) {
        float s = b2[t];
        for (int k = 0; k < 32; k++) s += y1[k] * W2[k * 16 + t];
        y2[t] = fmaxf(s, 0.f);
    }
    __syncthreads();
    if (t < NC) {
        float s = b3[t];
        for (int k = 0; k < 16; k++) s += y2[k] * W3[k * NC + t];
        out[g * NC + t] = s;
    }
}

extern "C" void kernel_launch(void* const* d_in, const int* in_sizes, int n_in,
                              void* d_out, int out_size, void* d_ws, size_t ws_size,
                              hipStream_t stream) {
    const float* x     = (const float*)d_in[0];
    const int*   ei    = (const int*)d_in[1];
    const int*   batch = (const int*)d_in[2];
    const float* W_in  = (const float*)d_in[3];
    const float* b_in  = (const float*)d_in[4];
    const float* W_hid = (const float*)d_in[5];
    const float* b_hid = (const float*)d_in[6];
    const float* gamma = (const float*)d_in[7];
    const float* beta  = (const float*)d_in[8];
    const float* W1    = (const float*)d_in[9];
    const float* b1    = (const float*)d_in[10];
    const float* W2    = (const float*)d_in[11];
    const float* b2    = (const float*)d_in[12];
    const float* W3    = (const float*)d_in[13];
    const float* b3    = (const float*)d_in[14];
    float* out = (float*)d_out;

    const int* src = ei;
    const int* dst = ei + NE;

    // ---- workspace layout (all chunks 16B-aligned) ----
    int*   deg_i  = (int*)d_ws;              // 50048
    int*   ebase  = deg_i + 50048;           // 50056
    int*   cursor = ebase + 50056;           // 50048
    int*   eidx   = cursor + 50048;          // 800000
    int*   bsum   = eidx + 800000;           // 256
    int*   gstart = bsum + 256;              // 72
    float* dis    = (float*)(gstart + 72);   // 50048
    float* enorm  = dis + 50048;             // 800000
    float* hw     = enorm + 800000;          // NN*H
    float* conv   = hw + (long)NN * H;       // NN*H
    float* h      = conv + (long)NN * H;     // NN*H
    float* pbn    = h + (long)NN * H;        // 12500*128
    float* pbn2   = pbn + (long)GATHER_BLOCKS * 128;  // 125*128
    float* bnsc   = pbn2 + BNRED_BLOCKS * 128;        // 128
    float* pooled = bnsc + 128;              // NG*H

    const int NB_GEMM = (NN + 63) / 64;        // 782
    const int NB_E    = (NE + 255) / 256;      // 3125
    const int NB_N    = (NN + 255) / 256;      // 196

    // ---- CSR build ----
    hipMemsetAsync(deg_i, 0, 50048 * sizeof(int), stream);
    hipMemsetAsync(cursor, 0, 50048 * sizeof(int), stream);
    count_deg_kernel<<<NB_E, 256, 0, stream>>>(dst, deg_i);
    make_dis_kernel<<<NB_N, 256, 0, stream>>>(deg_i, dis);
    scan1_kernel<<<NB_SCAN, 256, 0, stream>>>(deg_i, ebase, bsum);
    scan2_kernel<<<1, 256, 0, stream>>>(bsum);
    scan3_kernel<<<NB_N, 256, 0, stream>>>(ebase, bsum);
    fill_kernel<<<NB_E, 256, 0, stream>>>(src, dst, ebase, cursor, dis, eidx, enorm);
    gstart_kernel<<<1, 128, 0, stream>>>(batch, gstart);

    // ---- layer 0: GCNConv(x, W_in) + ReLU ----
    gemm_fin_kernel<<<NB_GEMM, 256, 0, stream>>>(x, W_in, hw);
    gather_kernel<0><<<GATHER_BLOCKS, 256, 0, stream>>>(hw, ebase, eidx, enorm, dis, b_in, h, nullptr);

    // ---- hidden layers (BN+ReLU fused into the next consumer) ----
    for (int l = 0; l < 3; l++) {
        if (l == 0)
            gemm_hid_kernel<0><<<NB_GEMM, 256, 0, stream>>>(h, W_hid, nullptr, hw);
        else
            gemm_hid_kernel<1><<<NB_GEMM, 256, 0, stream>>>(conv, W_hid + (long)l * H * H, bnsc, hw);
        gather_kernel<1><<<GATHER_BLOCKS, 256, 0, stream>>>(hw, ebase, eidx, enorm, dis,
                                                            b_hid + (long)l * H, conv, pbn);
        bnredA_kernel<<<BNRED_BLOCKS, 256, 0, stream>>>(pbn, pbn2);
        bnredB_kernel<<<1, 256, 0, stream>>>(pbn2, gamma, beta, bnsc);
    }

    // ---- pooling (fused BN+ReLU) + MLP ----
    pool_bn_kernel<<<NG, 256, 0, stream>>>(conv, bnsc, gstart, pooled);
    mlp_kernel<<<NG, H, 0, stream>>>(pooled, W1, b1, W2, b2, W3, b3, out);
}

// Round 9
// 609.718 us; speedup vs baseline: 3.5010x; 1.0847x over previous
//
#include <hip/hip_runtime.h>

#define NN 50000
#define NE 800000
#define FIN 128
#define H 64
#define NG 64
#define NC 10
#define EPS 1e-5f
#define NB_SCAN 196          // ceil(NN/256)
#define GATHER_BLOCKS 12500  // NN/4 exactly
#define BNRED_BLOCKS 125     // 12500 = 125 * 100

// ---------------- degree (int) ----------------
__global__ void count_deg_kernel(const int* __restrict__ dst, int* __restrict__ deg) {
    int e = blockIdx.x * blockDim.x + threadIdx.x;
    if (e < NE) atomicAdd(&deg[dst[e]], 1);
}

// ---------------- scan stage 1 (+ dis = rsqrt(deg+1)) ----------------
__global__ void scan1_kernel(const int* __restrict__ deg, int* __restrict__ ebase,
                             int* __restrict__ bsum, float* __restrict__ dis) {
    __shared__ int s[256];
    int t = threadIdx.x;
    int i = blockIdx.x * 256 + t;
    int v = (i < NN) ? deg[i] : 0;
    if (i < NN) dis[i] = rsqrtf((float)v + 1.0f);
    s[t] = v;
    for (int off = 1; off < 256; off <<= 1) {
        __syncthreads();
        int add = (t >= off) ? s[t - off] : 0;
        __syncthreads();
        s[t] += add;
    }
    __syncthreads();
    if (i < NN) ebase[i] = s[t] - v;
    if (t == 255) bsum[blockIdx.x] = s[255];
}

// ---------------- scan stage 2 (+ graph boundaries binary search) ----------------
__global__ void scan2_kernel(int* __restrict__ bsum, const int* __restrict__ batch,
                             int* __restrict__ gstart) {
    int t = threadIdx.x;
    if (t <= NG) {  // batch is sorted
        int lo = 0, hi = NN;
        while (lo < hi) {
            int mid = (lo + hi) >> 1;
            if (batch[mid] < t) lo = mid + 1; else hi = mid;
        }
        gstart[t] = lo;
    }
    __shared__ int s[256];
    int v = (t < NB_SCAN) ? bsum[t] : 0;
    s[t] = v;
    for (int off = 1; off < 256; off <<= 1) {
        __syncthreads();
        int add = (t >= off) ? s[t - off] : 0;
        __syncthreads();
        s[t] += add;
    }
    __syncthreads();
    if (t < NB_SCAN) bsum[t] = s[t] - v;
}

__global__ void scan3_kernel(int* __restrict__ ebase, const int* __restrict__ bsum) {
    int i = blockIdx.x * blockDim.x + threadIdx.x;
    if (i < NN) ebase[i] += bsum[i >> 8];
    if (i == 0) ebase[NN] = NE;
}

// ---------------- CSR fill (eidx only; norms folded into hw rows) ----------------
__global__ void fill_kernel(const int* __restrict__ src, const int* __restrict__ dst,
                            const int* __restrict__ ebase, int* __restrict__ cursor,
                            int* __restrict__ eidx) {
    int e = blockIdx.x * blockDim.x + threadIdx.x;
    if (e < NE) {
        int d = dst[e];
        int slot = ebase[d] + atomicAdd(&cursor[d], 1);
        eidx[slot] = src[e];
    }
}

// ---------------- GEMM layer 0: hw[r] = dis[r] * (x[r] @ W) ----------------
__global__ __launch_bounds__(256, 4) void gemm_fin_kernel(const float* __restrict__ A,
                                                          const float* __restrict__ W,
                                                          const float* __restrict__ dis,
                                                          float* __restrict__ outp) {
    __shared__ float Al[64][65];
    __shared__ float Wl[64 * H];
    const int tid = threadIdx.x;
    const int r0 = blockIdx.x * 64;
    const int row = tid >> 2;
    const int cb  = (tid & 3) << 4;
    float acc[16];
#pragma unroll
    for (int j = 0; j < 16; j++) acc[j] = 0.f;

    for (int k0 = 0; k0 < FIN; k0 += 64) {
        for (int idx = tid; idx < 64 * H; idx += 256) Wl[idx] = W[k0 * H + idx];
        for (int idx = tid; idx < 64 * 64; idx += 256) {
            int r = idx >> 6, c = idx & 63;
            int gr = r0 + r;
            Al[r][c] = (gr < NN) ? A[(long)gr * FIN + k0 + c] : 0.f;
        }
        __syncthreads();
#pragma unroll
        for (int k = 0; k < 64; k++) {
            float a = Al[row][k];
#pragma unroll
            for (int j = 0; j < 16; j++) acc[j] = fmaf(a, Wl[k * H + cb + j], acc[j]);
        }
        __syncthreads();
    }
    int gr = r0 + row;
    if (gr < NN) {
        float ds = dis[gr];
#pragma unroll
        for (int j = 0; j < 16; j++) acc[j] *= ds;
        float4* o = reinterpret_cast<float4*>(&outp[(long)gr * H + cb]);
        o[0] = make_float4(acc[0], acc[1], acc[2], acc[3]);
        o[1] = make_float4(acc[4], acc[5], acc[6], acc[7]);
        o[2] = make_float4(acc[8], acc[9], acc[10], acc[11]);
        o[3] = make_float4(acc[12], acc[13], acc[14], acc[15]);
    }
}

// ---------------- hidden GEMM: hw[r] = dis[r] * (act(A[r]) @ W) ----------------
// DO_BN=1: prologue reduces pbn2 -> scale/shift; act(a) = relu(a*sc + sh)
template <int DO_BN>
__global__ __launch_bounds__(256, 4) void gemm_hid_kernel(const float* __restrict__ A,
                                                          const float* __restrict__ W,
                                                          const float* __restrict__ pbn2,
                                                          const float* __restrict__ gamma,
                                                          const float* __restrict__ beta,
                                                          const float* __restrict__ dis,
                                                          float* __restrict__ outp) {
    __shared__ float Al[64][65];
    __shared__ float Wl[64 * H];
    __shared__ float bns[128];
    __shared__ float tot[128];
    const int tid = threadIdx.x;
    if (DO_BN) {
        if (tid < 128) {
            float s = 0.f;
            for (int r = 0; r < BNRED_BLOCKS; ++r) s += pbn2[(long)r * 128 + tid];
            tot[tid] = s;
        }
        __syncthreads();
        if (tid < H) {
            float mu  = tot[tid] * (1.0f / NN);
            float var = tot[H + tid] * (1.0f / NN) - mu * mu;
            float sc  = rsqrtf(var + EPS) * gamma[tid];
            bns[tid]     = sc;
            bns[H + tid] = beta[tid] - mu * sc;
        }
        __syncthreads();
    }
    const int r0 = blockIdx.x * 64;
    const int row = tid >> 2;
    const int cb  = (tid & 3) << 4;
    float acc[16];
#pragma unroll
    for (int j = 0; j < 16; j++) acc[j] = 0.f;

    for (int idx = tid; idx < 64 * H; idx += 256) Wl[idx] = W[idx];
    for (int idx = tid; idx < 64 * 64; idx += 256) {
        int r = idx >> 6, c = idx & 63;
        int gr = r0 + r;
        float a = (gr < NN) ? A[(long)gr * H + c] : 0.f;
        if (DO_BN) a = fmaxf(fmaf(a, bns[c], bns[64 + c]), 0.f);
        Al[r][c] = a;
    }
    __syncthreads();
#pragma unroll
    for (int k = 0; k < 64; k++) {
        float a = Al[row][k];
#pragma unroll
        for (int j = 0; j < 16; j++) acc[j] = fmaf(a, Wl[k * H + cb + j], acc[j]);
    }
    int gr = r0 + row;
    if (gr < NN) {
        float ds = dis[gr];
#pragma unroll
        for (int j = 0; j < 16; j++) acc[j] *= ds;
        float4* o = reinterpret_cast<float4*>(&outp[(long)gr * H + cb]);
        o[0] = make_float4(acc[0], acc[1], acc[2], acc[3]);
        o[1] = make_float4(acc[4], acc[5], acc[6], acc[7]);
        o[2] = make_float4(acc[8], acc[9], acc[10], acc[11]);
        o[3] = make_float4(acc[12], acc[13], acc[14], acc[15]);
    }
}

// ---------------- CSR gather: wave/node, 16 lanes x float4, 4 edge groups, x2 unroll --
// out_i = dis_i * (sum_{j in N(i)} hw'_j + hw'_i) + b   where hw' rows carry dis_j
// MODE 0: relu epilogue (layer 0).  MODE 1: raw + BN partials (hidden).
template <int MODE>
__global__ __launch_bounds__(256) void gather_kernel(const float* __restrict__ hw,
                                                     const int* __restrict__ ebase,
                                                     const int* __restrict__ eidx,
                                                     const float* __restrict__ dis,
                                                     const float* __restrict__ bias,
                                                     float* __restrict__ outp,
                                                     float* __restrict__ pbn) {
    __shared__ float ls[H], lss[H];
    if (MODE == 1) {
        if (threadIdx.x < H) { ls[threadIdx.x] = 0.f; lss[threadIdx.x] = 0.f; }
        __syncthreads();
    }
    const int node = blockIdx.x * 4 + (threadIdx.x >> 6);  // grid exact: node < NN
    const int lane = threadIdx.x & 63;
    const int grp  = lane >> 4;          // edge sub-group 0..3
    const int c4   = (lane & 15) << 2;   // channel base
    const int e0 = ebase[node], e1 = ebase[node + 1];
    float4 acc = make_float4(0.f, 0.f, 0.f, 0.f);
    int e = e0 + grp;
    for (; e + 4 < e1; e += 8) {
        int s0 = eidx[e], s1 = eidx[e + 4];
        const float4 v0 = *reinterpret_cast<const float4*>(&hw[(long)s0 * H + c4]);
        const float4 v1 = *reinterpret_cast<const float4*>(&hw[(long)s1 * H + c4]);
        acc.x += v0.x + v1.x;
        acc.y += v0.y + v1.y;
        acc.z += v0.z + v1.z;
        acc.w += v0.w + v1.w;
    }
    if (e < e1) {
        const float4 v0 = *reinterpret_cast<const float4*>(&hw[(long)eidx[e] * H + c4]);
        acc.x += v0.x; acc.y += v0.y; acc.z += v0.z; acc.w += v0.w;
    }
#pragma unroll
    for (int m = 16; m <= 32; m <<= 1) {
        acc.x += __shfl_xor(acc.x, m, 64);
        acc.y += __shfl_xor(acc.y, m, 64);
        acc.z += __shfl_xor(acc.z, m, 64);
        acc.w += __shfl_xor(acc.w, m, 64);
    }
    const float4 self = *reinterpret_cast<const float4*>(&hw[(long)node * H + c4]);
    float ds = dis[node];
    float4 v;
    v.x = fmaf(acc.x + self.x, ds, bias[c4 + 0]);
    v.y = fmaf(acc.y + self.y, ds, bias[c4 + 1]);
    v.z = fmaf(acc.z + self.z, ds, bias[c4 + 2]);
    v.w = fmaf(acc.w + self.w, ds, bias[c4 + 3]);
    if (MODE == 0) {
        v.x = fmaxf(v.x, 0.f); v.y = fmaxf(v.y, 0.f);
        v.z = fmaxf(v.z, 0.f); v.w = fmaxf(v.w, 0.f);
    }
    if (grp == 0) {
        *reinterpret_cast<float4*>(&outp[(long)node * H + c4]) = v;
        if (MODE == 1) {
            atomicAdd(&ls[c4 + 0], v.x); atomicAdd(&lss[c4 + 0], v.x * v.x);
            atomicAdd(&ls[c4 + 1], v.y); atomicAdd(&lss[c4 + 1], v.y * v.y);
            atomicAdd(&ls[c4 + 2], v.z); atomicAdd(&lss[c4 + 2], v.z * v.z);
            atomicAdd(&ls[c4 + 3], v.w); atomicAdd(&lss[c4 + 3], v.w * v.w);
        }
    }
    if (MODE == 1) {
        __syncthreads();
        if (threadIdx.x < H) {
            pbn[(long)blockIdx.x * 128 + threadIdx.x] = ls[threadIdx.x];
            pbn[(long)blockIdx.x * 128 + H + threadIdx.x] = lss[threadIdx.x];
        }
    }
}

// ---------------- BN partial reduction (coalesced): 12500x128 -> 125x128 ----------------
__global__ void bnredA_kernel(const float* __restrict__ pbn, float* __restrict__ pbn2) {
    int c = threadIdx.x & 127;
    int half = threadIdx.x >> 7;
    int r0 = blockIdx.x * 100;
    float s = 0.f;
    for (int r = r0 + half; r < r0 + 100; r += 2) s += pbn[(long)r * 128 + c];
    __shared__ float red[256];
    red[threadIdx.x] = s;
    __syncthreads();
    if (half == 0) pbn2[(long)blockIdx.x * 128 + c] = red[c] + red[128 + c];
}

// ---------------- pool (fused BN+ReLU) + MLP readout, one block per graph ------------
__global__ void pool_mlp_kernel(const float* __restrict__ conv, const float* __restrict__ pbn2,
                                const float* __restrict__ gamma, const float* __restrict__ beta,
                                const int* __restrict__ gstart,
                                const float* __restrict__ W1, const float* __restrict__ b1,
                                const float* __restrict__ W2, const float* __restrict__ b2,
                                const float* __restrict__ W3, const float* __restrict__ b3,
                                float* __restrict__ out) {
    __shared__ float tot[128];
    __shared__ float bns[128];
    __shared__ float red[256];
    __shared__ float pl[H], y1[32], y2[16];
    const int t = threadIdx.x;
    const int g = blockIdx.x;
    if (t < 128) {
        float s = 0.f;
        for (int r = 0; r < BNRED_BLOCKS; ++r) s += pbn2[(long)r * 128 + t];
        tot[t] = s;
    }
    __syncthreads();
    if (t < H) {
        float mu  = tot[t] * (1.0f / NN);
        float var = tot[H + t] * (1.0f / NN) - mu * mu;
        float sc  = rsqrtf(var + EPS) * gamma[t];
        bns[t]     = sc;
        bns[H + t] = beta[t] - mu * sc;
    }
    __syncthreads();
    const int n0 = gstart[g], n1 = gstart[g + 1];
    const int sub = t >> 6, lane = t & 63;
    float sc = bns[lane], sh = bns[H + lane];
    float s = 0.f;
    for (int n = n0 + sub; n < n1; n += 4)
        s += fmaxf(fmaf(conv[(long)n * H + lane], sc, sh), 0.f);
    red[t] = s;
    __syncthreads();
    if (sub == 0) {
        float inv = 1.0f / fmaxf((float)(n1 - n0), 1.0f);
        pl[lane] = (red[lane] + red[64 + lane] + red[128 + lane] + red[192 + lane]) * inv;
    }
    __syncthreads();
    if (t < 32) {
        float v = b1[t];
        for (int k = 0; k < H; k++) v = fmaf(pl[k], W1[k * 32 + t], v);
        y1[t] = fmaxf(v, 0.f);
    }
    __syncthreads();
    if (t < 16) {
        float v = b2[t];
        for (int k = 0; k < 32; k++) v = fmaf(y1[k], W2[k * 16 + t], v);
        y2[t] = fmaxf(v, 0.f);
    }
    __syncthreads();
    if (t < NC) {
        float v = b3[t];
        for (int k = 0; k < 16; k++) v = fmaf(y2[k], W3[k * NC + t], v);
        out[(long)g * NC + t] = v;
    }
}

extern "C" void kernel_launch(void* const* d_in, const int* in_sizes, int n_in,
                              void* d_out, int out_size, void* d_ws, size_t ws_size,
                              hipStream_t stream) {
    const float* x     = (const float*)d_in[0];
    const int*   ei    = (const int*)d_in[1];
    const int*   batch = (const int*)d_in[2];
    const float* W_in  = (const float*)d_in[3];
    const float* b_in  = (const float*)d_in[4];
    const float* W_hid = (const float*)d_in[5];
    const float* b_hid = (const float*)d_in[6];
    const float* gamma = (const float*)d_in[7];
    const float* beta  = (const float*)d_in[8];
    const float* W1    = (const float*)d_in[9];
    const float* b1    = (const float*)d_in[10];
    const float* W2    = (const float*)d_in[11];
    const float* b2    = (const float*)d_in[12];
    const float* W3    = (const float*)d_in[13];
    const float* b3    = (const float*)d_in[14];
    float* out = (float*)d_out;

    const int* src = ei;
    const int* dst = ei + NE;

    // ---- workspace layout (deg|cursor adjacent -> single memset) ----
    int*   deg_i  = (int*)d_ws;              // 50048
    int*   cursor = deg_i + 50048;           // 50048
    int*   ebase  = cursor + 50048;          // 50056
    int*   eidx   = ebase + 50056;           // 800000
    int*   bsum   = eidx + 800000;           // 256
    int*   gstart = bsum + 256;              // 72
    float* dis    = (float*)(gstart + 72);   // 50048
    float* hw     = dis + 50048;             // NN*H (dis-scaled)
    float* conv   = hw + (long)NN * H;       // NN*H
    float* h      = conv + (long)NN * H;     // NN*H
    float* pbn    = h + (long)NN * H;        // 12500*128
    float* pbn2   = pbn + (long)GATHER_BLOCKS * 128;  // 125*128

    const int NB_GEMM = (NN + 63) / 64;        // 782
    const int NB_E    = (NE + 255) / 256;      // 3125
    const int NB_N    = (NN + 255) / 256;      // 196

    // ---- CSR build ----
    hipMemsetAsync(deg_i, 0, 2 * 50048 * sizeof(int), stream);
    count_deg_kernel<<<NB_E, 256, 0, stream>>>(dst, deg_i);
    scan1_kernel<<<NB_SCAN, 256, 0, stream>>>(deg_i, ebase, bsum, dis);
    scan2_kernel<<<1, 256, 0, stream>>>(bsum, batch, gstart);
    scan3_kernel<<<NB_N, 256, 0, stream>>>(ebase, bsum);
    fill_kernel<<<NB_E, 256, 0, stream>>>(src, dst, ebase, cursor, eidx);

    // ---- layer 0 ----
    gemm_fin_kernel<<<NB_GEMM, 256, 0, stream>>>(x, W_in, dis, hw);
    gather_kernel<0><<<GATHER_BLOCKS, 256, 0, stream>>>(hw, ebase, eidx, dis, b_in, h, nullptr);

    // ---- hidden layers ----
    gemm_hid_kernel<0><<<NB_GEMM, 256, 0, stream>>>(h, W_hid, nullptr, nullptr, nullptr, dis, hw);
    gather_kernel<1><<<GATHER_BLOCKS, 256, 0, stream>>>(hw, ebase, eidx, dis, b_hid, conv, pbn);
    bnredA_kernel<<<BNRED_BLOCKS, 256, 0, stream>>>(pbn, pbn2);
    for (int l = 1; l < 3; l++) {
        gemm_hid_kernel<1><<<NB_GEMM, 256, 0, stream>>>(conv, W_hid + (long)l * H * H, pbn2,
                                                        gamma, beta, dis, hw);
        gather_kernel<1><<<GATHER_BLOCKS, 256, 0, stream>>>(hw, ebase, eidx, dis,
                                                            b_hid + (long)l * H, conv, pbn);
        bnredA_kernel<<<BNRED_BLOCKS, 256, 0, stream>>>(pbn, pbn2);
    }

    // ---- pool (+BN+ReLU) + MLP ----
    pool_mlp_kernel<<<NG, 256, 0, stream>>>(conv, pbn2, gamma, beta, gstart,
                                            W1, b1, W2, b2, W3, b3, out);
}